// Round 6
// baseline (112.287 us; speedup 1.0000x reference)
//
#include <hip/hip_runtime.h>
#include <hip/hip_bf16.h>

typedef __attribute__((ext_vector_type(8))) short short8;
typedef __attribute__((ext_vector_type(4))) float f32x4;
typedef __attribute__((ext_vector_type(4))) unsigned short u16x4;
typedef unsigned short u16;

#define Bn 8
#define Tn 2048
#define Cn 1024
#define Hn 64
#define Mrows (Bn * Tn)  // 16384
#define UPB 320          // split-K work units per batch
#define SLOTF 1056       // floats per partial slot: 1024 o + 16 m + 16 l

__device__ __forceinline__ u16 bfu(float f) {
    __hip_bfloat16 h = __float2bfloat16(f);
    union { __hip_bfloat16 h; u16 u; } c; c.h = h; return c.u;
}

__device__ __forceinline__ short8 cvt8(f32x4 a0, f32x4 a1) {
    short8 r;
    r[0] = (short)bfu(a0[0]); r[1] = (short)bfu(a0[1]);
    r[2] = (short)bfu(a0[2]); r[3] = (short)bfu(a0[3]);
    r[4] = (short)bfu(a1[0]); r[5] = (short)bfu(a1[1]);
    r[6] = (short)bfu(a1[2]); r[7] = (short)bfu(a1[3]);
    return r;
}

// All three W [1024][64] f32 -> wt [3][64][1024] bf16 (transposed), scale folded.
__global__ void convert_w3(const float* __restrict__ Wq, const float* __restrict__ Wk,
                           const float* __restrict__ Wv, u16* __restrict__ wt, float qscale) {
    int widx = blockIdx.x * 256 + threadIdx.x;          // 0 .. 3*65536-1
    int mat = widx >> 16;
    int rem = widx & 65535;
    int k = rem >> 6, n = rem & 63;
    const float* W = mat == 0 ? Wq : (mat == 1 ? Wk : Wv);
    float s = mat == 0 ? qscale : 1.0f;
    wt[(size_t)mat * 65536 + n * Cn + k] = bfu(W[rem] * s);
}

// x [16384][1024] f32 @ wt^T -> q,k bf16 [16384][64] + vt bf16 [8][64][2048].
// Barrier-free + explicit 2-stage register prefetch pipeline (named stage vars
// so the compiler cannot sink loads to point-of-use; see round-5 post-mortem:
// VGPR=52 proved it had built no pipeline, 2300 cy/iter exposed latency).
__global__ __launch_bounds__(256) void qkv_proj(const float* __restrict__ x,
                                                const u16* __restrict__ wt,
                                                u16* __restrict__ qk,
                                                u16* __restrict__ vt) {
    const int tid = threadIdx.x;
    const int lane = tid & 63;
    const int wn = tid >> 6;          // 0..3 -> 48-col slice
    const int l15 = lane & 15;
    const int lhi = lane >> 4;
    const int row0 = blockIdx.x * 32;

    const float* xr0 = x + (size_t)(row0 + l15) * Cn + lhi * 8;
    const float* xr1 = xr0 + (size_t)16 * Cn;
    const u16* wb = wt + (size_t)(wn * 48 + l15) * Cn + lhi * 8;

    f32x4 c00 = {0.f,0.f,0.f,0.f}, c01 = c00, c02 = c00;
    f32x4 c10 = c00, c11 = c00, c12 = c00;

    short8 p0b0, p0b1, p0b2, p1b0, p1b1, p1b2;
    f32x4 p0a00, p0a01, p0a10, p0a11, p1a00, p1a01, p1a10, p1a11;

#define LOADST(s, off) do { \
    s##b0  = *(const short8*)(wb + (off)); \
    s##b1  = *(const short8*)(wb + 16 * Cn + (off)); \
    s##b2  = *(const short8*)(wb + 32 * Cn + (off)); \
    s##a00 = *(const f32x4*)(xr0 + (off)); \
    s##a01 = *(const f32x4*)(xr0 + (off) + 4); \
    s##a10 = *(const f32x4*)(xr1 + (off)); \
    s##a11 = *(const f32x4*)(xr1 + (off) + 4); \
} while (0)

#define COMPST(s) do { \
    short8 af0 = cvt8(s##a00, s##a01); \
    short8 af1 = cvt8(s##a10, s##a11); \
    c00 = __builtin_amdgcn_mfma_f32_16x16x32_bf16(af0, s##b0, c00, 0, 0, 0); \
    c01 = __builtin_amdgcn_mfma_f32_16x16x32_bf16(af0, s##b1, c01, 0, 0, 0); \
    c02 = __builtin_amdgcn_mfma_f32_16x16x32_bf16(af0, s##b2, c02, 0, 0, 0); \
    c10 = __builtin_amdgcn_mfma_f32_16x16x32_bf16(af1, s##b0, c10, 0, 0, 0); \
    c11 = __builtin_amdgcn_mfma_f32_16x16x32_bf16(af1, s##b1, c11, 0, 0, 0); \
    c12 = __builtin_amdgcn_mfma_f32_16x16x32_bf16(af1, s##b2, c12, 0, 0, 0); \
} while (0)

    LOADST(p0, 0);
    LOADST(p1, 32);
    for (int ko = 0; ko < Cn - 64; ko += 64) {
        COMPST(p0);
        LOADST(p0, ko + 64);
        COMPST(p1);
        LOADST(p1, ko + 96);
    }
    COMPST(p0);
    COMPST(p1);
#undef LOADST
#undef COMPST

    f32x4 acc[2][3] = {{c00, c01, c02}, {c10, c11, c12}};
    for (int mt = 0; mt < 2; ++mt) {
        const int growb = row0 + mt * 16 + lhi * 4;
        for (int nj = 0; nj < 3; ++nj) {
            int gcolb = wn * 48 + nj * 16 + l15;
            int mat = gcolb >> 6, lcol = gcolb & 63;
            if (mat < 2) {
                u16* dst = qk + (size_t)mat * (Mrows * Hn);
                for (int r = 0; r < 4; ++r)
                    dst[(size_t)(growb + r) * Hn + lcol] = bfu(acc[mt][nj][r]);
            } else {
                int b = growb >> 11, t = growb & 2047;
                u16x4 pk;
                pk[0] = bfu(acc[mt][nj][0]); pk[1] = bfu(acc[mt][nj][1]);
                pk[2] = bfu(acc[mt][nj][2]); pk[3] = bfu(acc[mt][nj][3]);
                *(u16x4*)(vt + ((size_t)b * Hn + lcol) * Tn + t) = pk;
            }
        }
    }
}

// Flash attention, causal, split-K. One wave per (16 q-rows, <=512-key chunk).
__global__ __launch_bounds__(64) void attn_fwd(const u16* __restrict__ q,
                                               const u16* __restrict__ k,
                                               const u16* __restrict__ vt,
                                               float* __restrict__ partial) {
    __shared__ u16 pl[16][72];
    const int lane = threadIdx.x;
    const int l15 = lane & 15, lhi = lane >> 4;
    const int bid = blockIdx.x;
    const int b = bid / UPB;
    const int u = bid - b * UPB;
    int qt, c;
    if (u < 32)       { qt = u;                  c = 0; }
    else if (u < 96)  { qt = 32 + ((u - 32) >> 1);  c = (u - 32) & 1; }
    else if (u < 192) { qt = 64 + (u - 96) / 3;     c = (u - 96) % 3; }
    else              { qt = 96 + ((u - 192) >> 2); c = (u - 192) & 3; }
    const int nkt = (qt >> 2) + 1;
    const int kb0 = c * 8;
    const int kbe = min(kb0 + 8, nkt);
    const int q0 = qt * 16;

    const u16* qb = q + (size_t)b * Tn * Hn;
    const u16* kbp = k + (size_t)b * Tn * Hn;
    const u16* vtb = vt + (size_t)b * Hn * Tn;

    short8 qf[2];
    for (int kc = 0; kc < 2; ++kc)
        qf[kc] = *(const short8*)(qb + (size_t)(q0 + l15) * Hn + kc * 32 + lhi * 8);

    float m = -1e30f, lpart = 0.f;   // per-lane: q-row = l15 (uniform across lhi)
    f32x4 o[4];
    for (int dt = 0; dt < 4; ++dt) o[dt] = f32x4{0.f, 0.f, 0.f, 0.f};

    for (int kbi = kb0; kbi < kbe; ++kbi) {
        const int k0 = kbi * 64;
        f32x4 sacc[4];
        for (int kt = 0; kt < 4; ++kt) sacc[kt] = f32x4{0.f, 0.f, 0.f, 0.f};
        // S^T = K·Q^T : D col = q (l15), D row = k-within-tile (lhi*4+r)
        for (int kc = 0; kc < 2; ++kc) {
            for (int kt = 0; kt < 4; ++kt) {
                short8 kf = *(const short8*)(kbp + (size_t)(k0 + kt * 16 + l15) * Hn + kc * 32 + lhi * 8);
                sacc[kt] = __builtin_amdgcn_mfma_f32_16x16x32_bf16(kf, qf[kc], sacc[kt], 0, 0, 0);
            }
        }
        if (kbi == nkt - 1) {  // diagonal tile: causal mask (per-lane, no shuffle)
            for (int kt = 0; kt < 4; ++kt)
                for (int r = 0; r < 4; ++r) {
                    int kg = k0 + kt * 16 + lhi * 4 + r;
                    if (kg > q0 + l15) sacc[kt][r] = -3.0e38f;
                }
        }
        f32x4 mx0, mx1;
        for (int e = 0; e < 4; ++e) {
            mx0[e] = fmaxf(sacc[0][e], sacc[1][e]);
            mx1[e] = fmaxf(sacc[2][e], sacc[3][e]);
        }
        float tmax = -3.0e38f;
        for (int e = 0; e < 4; ++e) tmax = fmaxf(tmax, fmaxf(mx0[e], mx1[e]));
        tmax = fmaxf(tmax, __shfl_xor(tmax, 16));
        tmax = fmaxf(tmax, __shfl_xor(tmax, 32));
        if (!__all(tmax <= m + 8.0f)) {   // defer-max (THR=8, log2 domain)
            float mnew = fmaxf(m, tmax);
            float corr = exp2f(m - mnew);
            m = mnew;
            lpart *= corr;
            for (int r = 0; r < 4; ++r) {
                float cr = __shfl(corr, lhi * 4 + r);
                for (int dt = 0; dt < 4; ++dt) o[dt][r] *= cr;
            }
        }
        float psum = 0.f;
        for (int kt = 0; kt < 4; ++kt)
            for (int r = 0; r < 4; ++r) {
                float p = exp2f(sacc[kt][r] - m);
                sacc[kt][r] = p;
                psum += p;
            }
        lpart += psum;
        for (int kt = 0; kt < 4; ++kt) {
            u16x4 pk;
            pk[0] = bfu(sacc[kt][0]); pk[1] = bfu(sacc[kt][1]);
            pk[2] = bfu(sacc[kt][2]); pk[3] = bfu(sacc[kt][3]);
            *(u16x4*)&pl[l15][kt * 16 + lhi * 4] = pk;
        }
        short8 pf[2];
        for (int kc = 0; kc < 2; ++kc)
            pf[kc] = *(const short8*)&pl[l15][kc * 32 + lhi * 8];
        for (int dt = 0; dt < 4; ++dt) {
            for (int kc = 0; kc < 2; ++kc) {
                short8 vf = *(const short8*)(vtb + (size_t)(dt * 16 + l15) * Tn + k0 + kc * 32 + lhi * 8);
                o[dt] = __builtin_amdgcn_mfma_f32_16x16x32_bf16(pf[kc], vf, o[dt], 0, 0, 0);
            }
        }
    }
    float lsum = lpart;
    lsum += __shfl_xor(lsum, 16);
    lsum += __shfl_xor(lsum, 32);

    float* ps = partial + (size_t)bid * SLOTF;
    for (int dt = 0; dt < 4; ++dt)
        for (int r = 0; r < 4; ++r)
            ps[(lhi * 4 + r) * 64 + dt * 16 + l15] = o[dt][r];
    if (lhi == 0) {
        ps[1024 + l15] = m;
        ps[1040 + l15] = lsum;
    }
}

// Combine <=4 split-K partials per (b, q-tile).
__global__ __launch_bounds__(256) void attn_reduce(const float* __restrict__ partial,
                                                   float* __restrict__ out) {
    const int bid = blockIdx.x;           // 0..1023
    const int b = bid >> 7, qt = bid & 127;
    const int nc = qt < 32 ? 1 : qt < 64 ? 2 : qt < 96 ? 3 : 4;
    const int base = b * UPB +
        (qt < 32 ? qt : qt < 64 ? 32 + 2 * (qt - 32)
                      : qt < 96 ? 96 + 3 * (qt - 64) : 192 + 4 * (qt - 96));
    const int d = threadIdx.x & 63;
    const int qr = threadIdx.x >> 6;
    for (int i = 0; i < 4; ++i) {
        const int qq = i * 4 + qr;
        float M = -3.0e38f;
        #pragma unroll
        for (int cc = 0; cc < 4; ++cc)
            if (cc < nc) M = fmaxf(M, partial[(size_t)(base + cc) * SLOTF + 1024 + qq]);
        float L = 0.f, acc = 0.f;
        #pragma unroll
        for (int cc = 0; cc < 4; ++cc)
            if (cc < nc) {
                const float* ps = partial + (size_t)(base + cc) * SLOTF;
                float w = exp2f(ps[1024 + qq] - M);
                L += ps[1040 + qq] * w;
                acc += ps[qq * 64 + d] * w;
            }
        out[((size_t)b * Tn + qt * 16 + qq) * Hn + d] = acc / L;
    }
}

extern "C" void kernel_launch(void* const* d_in, const int* in_sizes, int n_in,
                              void* d_out, int out_size, void* d_ws, size_t ws_size,
                              hipStream_t stream) {
    const float* x = (const float*)d_in[0];
    const float* Wq = (const float*)d_in[1];
    const float* Wk = (const float*)d_in[2];
    const float* Wv = (const float*)d_in[3];
    float* out = (float*)d_out;
    char* ws = (char*)d_ws;

    u16* wt = (u16*)ws;                                    // [3][64][1024] bf16   (384 KB)
    u16* qk = (u16*)(ws + 3 * Hn * Cn * 2);                // 2 x [16384][64] bf16 (4 MB)
    u16* vt = qk + 2 * (size_t)Mrows * Hn;                 // [8][64][2048] bf16   (2 MB)
    float* partial = (float*)(ws + 3 * Hn * Cn * 2
                              + 2 * (size_t)Mrows * Hn * 2
                              + (size_t)Bn * Hn * Tn * 2); // 2560 x 1056 f32      (10.8 MB)

    const float qscale = 0.04508422002778011f;  // C^-0.5 * log2(e)
    convert_w3<<<768, 256, 0, stream>>>(Wq, Wk, Wv, wt, qscale);
    qkv_proj<<<512, 256, 0, stream>>>(x, wt, qk, vt);
    attn_fwd<<<Bn * UPB, 64, 0, stream>>>(qk, qk + (size_t)Mrows * Hn, vt, partial);
    attn_reduce<<<128 * Bn, 256, 0, stream>>>(partial, out);
}

// Round 7
// 85.278 us; speedup vs baseline: 1.3167x; 1.3167x over previous
//
#include <hip/hip_runtime.h>
#include <hip/hip_bf16.h>

typedef __attribute__((ext_vector_type(8))) short short8;
typedef __attribute__((ext_vector_type(4))) float f32x4;
typedef __attribute__((ext_vector_type(4))) unsigned short u16x4;
typedef unsigned short u16;

#define Bn 8
#define Tn 2048
#define Cn 1024
#define Hn 64
#define Mrows (Bn * Tn)  // 16384
#define UPB 320          // split-K work units per batch
#define SLOTF 1056       // floats per partial slot: 1024 o + 16 m + 16 l

__device__ __forceinline__ u16 bfu(float f) {
    __hip_bfloat16 h = __float2bfloat16(f);
    union { __hip_bfloat16 h; u16 u; } c; c.h = h; return c.u;
}

// All three W [1024][64] f32 -> wt [3][64][1024] bf16 (transposed), scale folded.
__global__ void convert_w3(const float* __restrict__ Wq, const float* __restrict__ Wk,
                           const float* __restrict__ Wv, u16* __restrict__ wt, float qscale) {
    int widx = blockIdx.x * 256 + threadIdx.x;          // 0 .. 3*65536-1
    int mat = widx >> 16;
    int rem = widx & 65535;
    int k = rem >> 6, n = rem & 63;
    const float* W = mat == 0 ? Wq : (mat == 1 ? Wk : Wv);
    float s = mat == 0 ? qscale : 1.0f;
    wt[(size_t)mat * 65536 + n * Cn + k] = bfu(W[rem] * s);
}

// x [16384][1024] f32 @ wt^T -> q,k bf16 [16384][64] + vt bf16 [8][64][2048].
// Round-6 postmortem: all scattered-load variants stuck at ~4400 cy/K-step
// (16x 64B transactions per load instr). This version makes every global load
// wave-contiguous: A staged f32x4-coalesced -> cvt -> padded LDS; B staged
// once per block into LDS (4x fewer B transactions, shared by 4 waves).
// M-tile 16, grid 1024 (4 blocks/CU), 256 thr, LDS ~30 KB.
__global__ __launch_bounds__(256, 4) void qkv_proj(const float* __restrict__ x,
                                                   const u16* __restrict__ wt,
                                                   u16* __restrict__ qk,
                                                   u16* __restrict__ vt) {
    __shared__ u16 As[16][72];   // bf16, pad->+8: <=2-way bank conflicts
    __shared__ u16 Bs[192][72];
    const int tid = threadIdx.x;
    const int lane = tid & 63;
    const int wn = tid >> 6;          // 0..3 -> 48-col slice
    const int l15 = lane & 15;
    const int lhi = lane >> 4;
    const int row0 = blockIdx.x * 16;

    const int arow = tid >> 4;        // 0..15
    const int ac4 = (tid & 15) * 4;   // f32 col 0..60
    const float* asrc = x + (size_t)(row0 + arow) * Cn + ac4;

    f32x4 acc[3];
    for (int nj = 0; nj < 3; ++nj) acc[nj] = f32x4{0.f, 0.f, 0.f, 0.f};

    for (int ko = 0; ko < Cn; ko += 64) {
        __syncthreads();
        // A: one coalesced f32x4 per thread (wave = 4 rows x 256B segments)
        f32x4 av = *(const f32x4*)(asrc + ko);
        u16x4 ab;
        ab[0] = bfu(av[0]); ab[1] = bfu(av[1]);
        ab[2] = bfu(av[2]); ab[3] = bfu(av[3]);
        *(u16x4*)&As[arow][ac4] = ab;
        // B: 6 coalesced 16B chunks per thread (wave = 8 rows x 128B segments)
        #pragma unroll
        for (int i = 0; i < 6; ++i) {
            int chunk = tid + 256 * i;            // 0..1535
            int brow = chunk >> 3;                // 0..191
            int bc8 = (chunk & 7) * 8;            // 0..56
            short8 bv = *(const short8*)(wt + (size_t)brow * Cn + ko + bc8);
            *(short8*)&Bs[brow][bc8] = bv;
        }
        __syncthreads();
        #pragma unroll
        for (int kc = 0; kc < 2; ++kc) {
            short8 af = *(const short8*)&As[l15][kc * 32 + lhi * 8];
            short8 bf0 = *(const short8*)&Bs[wn * 48 + l15][kc * 32 + lhi * 8];
            short8 bf1 = *(const short8*)&Bs[wn * 48 + 16 + l15][kc * 32 + lhi * 8];
            short8 bf2 = *(const short8*)&Bs[wn * 48 + 32 + l15][kc * 32 + lhi * 8];
            acc[0] = __builtin_amdgcn_mfma_f32_16x16x32_bf16(af, bf0, acc[0], 0, 0, 0);
            acc[1] = __builtin_amdgcn_mfma_f32_16x16x32_bf16(af, bf1, acc[1], 0, 0, 0);
            acc[2] = __builtin_amdgcn_mfma_f32_16x16x32_bf16(af, bf2, acc[2], 0, 0, 0);
        }
    }

    const int growb = row0 + lhi * 4;
    for (int nj = 0; nj < 3; ++nj) {
        int gcolb = wn * 48 + nj * 16 + l15;
        int mat = gcolb >> 6, lcol = gcolb & 63;
        if (mat < 2) {
            u16* dst = qk + (size_t)mat * (Mrows * Hn);
            for (int r = 0; r < 4; ++r)
                dst[(size_t)(growb + r) * Hn + lcol] = bfu(acc[nj][r]);
        } else {
            int b = growb >> 11, t = growb & 2047;
            u16x4 pk;
            pk[0] = bfu(acc[nj][0]); pk[1] = bfu(acc[nj][1]);
            pk[2] = bfu(acc[nj][2]); pk[3] = bfu(acc[nj][3]);
            *(u16x4*)(vt + ((size_t)b * Hn + lcol) * Tn + t) = pk;
        }
    }
}

// Flash attention, causal, split-K. One wave per (16 q-rows, <=512-key chunk).
__global__ __launch_bounds__(64) void attn_fwd(const u16* __restrict__ q,
                                               const u16* __restrict__ k,
                                               const u16* __restrict__ vt,
                                               float* __restrict__ partial) {
    __shared__ u16 pl[16][72];
    const int lane = threadIdx.x;
    const int l15 = lane & 15, lhi = lane >> 4;
    const int bid = blockIdx.x;
    const int b = bid / UPB;
    const int u = bid - b * UPB;
    int qt, c;
    if (u < 32)       { qt = u;                  c = 0; }
    else if (u < 96)  { qt = 32 + ((u - 32) >> 1);  c = (u - 32) & 1; }
    else if (u < 192) { qt = 64 + (u - 96) / 3;     c = (u - 96) % 3; }
    else              { qt = 96 + ((u - 192) >> 2); c = (u - 192) & 3; }
    const int nkt = (qt >> 2) + 1;
    const int kb0 = c * 8;
    const int kbe = min(kb0 + 8, nkt);
    const int q0 = qt * 16;

    const u16* qb = q + (size_t)b * Tn * Hn;
    const u16* kbp = k + (size_t)b * Tn * Hn;
    const u16* vtb = vt + (size_t)b * Hn * Tn;

    short8 qf[2];
    for (int kc = 0; kc < 2; ++kc)
        qf[kc] = *(const short8*)(qb + (size_t)(q0 + l15) * Hn + kc * 32 + lhi * 8);

    float m = -1e30f, lpart = 0.f;   // per-lane: q-row = l15 (uniform across lhi)
    f32x4 o[4];
    for (int dt = 0; dt < 4; ++dt) o[dt] = f32x4{0.f, 0.f, 0.f, 0.f};

    for (int kbi = kb0; kbi < kbe; ++kbi) {
        const int k0 = kbi * 64;
        f32x4 sacc[4];
        for (int kt = 0; kt < 4; ++kt) sacc[kt] = f32x4{0.f, 0.f, 0.f, 0.f};
        // S^T = K·Q^T : D col = q (l15), D row = k-within-tile (lhi*4+r)
        for (int kc = 0; kc < 2; ++kc) {
            for (int kt = 0; kt < 4; ++kt) {
                short8 kf = *(const short8*)(kbp + (size_t)(k0 + kt * 16 + l15) * Hn + kc * 32 + lhi * 8);
                sacc[kt] = __builtin_amdgcn_mfma_f32_16x16x32_bf16(kf, qf[kc], sacc[kt], 0, 0, 0);
            }
        }
        if (kbi == nkt - 1) {  // diagonal tile: causal mask (per-lane, no shuffle)
            for (int kt = 0; kt < 4; ++kt)
                for (int r = 0; r < 4; ++r) {
                    int kg = k0 + kt * 16 + lhi * 4 + r;
                    if (kg > q0 + l15) sacc[kt][r] = -3.0e38f;
                }
        }
        f32x4 mx0, mx1;
        for (int e = 0; e < 4; ++e) {
            mx0[e] = fmaxf(sacc[0][e], sacc[1][e]);
            mx1[e] = fmaxf(sacc[2][e], sacc[3][e]);
        }
        float tmax = -3.0e38f;
        for (int e = 0; e < 4; ++e) tmax = fmaxf(tmax, fmaxf(mx0[e], mx1[e]));
        tmax = fmaxf(tmax, __shfl_xor(tmax, 16));
        tmax = fmaxf(tmax, __shfl_xor(tmax, 32));
        if (!__all(tmax <= m + 8.0f)) {   // defer-max (THR=8, log2 domain)
            float mnew = fmaxf(m, tmax);
            float corr = exp2f(m - mnew);
            m = mnew;
            lpart *= corr;
            for (int r = 0; r < 4; ++r) {
                float cr = __shfl(corr, lhi * 4 + r);
                for (int dt = 0; dt < 4; ++dt) o[dt][r] *= cr;
            }
        }
        float psum = 0.f;
        for (int kt = 0; kt < 4; ++kt)
            for (int r = 0; r < 4; ++r) {
                float p = exp2f(sacc[kt][r] - m);
                sacc[kt][r] = p;
                psum += p;
            }
        lpart += psum;
        for (int kt = 0; kt < 4; ++kt) {
            u16x4 pk;
            pk[0] = bfu(sacc[kt][0]); pk[1] = bfu(sacc[kt][1]);
            pk[2] = bfu(sacc[kt][2]); pk[3] = bfu(sacc[kt][3]);
            *(u16x4*)&pl[l15][kt * 16 + lhi * 4] = pk;
        }
        short8 pf[2];
        for (int kc = 0; kc < 2; ++kc)
            pf[kc] = *(const short8*)&pl[l15][kc * 32 + lhi * 8];
        for (int dt = 0; dt < 4; ++dt) {
            for (int kc = 0; kc < 2; ++kc) {
                short8 vf = *(const short8*)(vtb + (size_t)(dt * 16 + l15) * Tn + k0 + kc * 32 + lhi * 8);
                o[dt] = __builtin_amdgcn_mfma_f32_16x16x32_bf16(pf[kc], vf, o[dt], 0, 0, 0);
            }
        }
    }
    float lsum = lpart;
    lsum += __shfl_xor(lsum, 16);
    lsum += __shfl_xor(lsum, 32);

    float* ps = partial + (size_t)bid * SLOTF;
    for (int dt = 0; dt < 4; ++dt)
        for (int r = 0; r < 4; ++r)
            ps[(lhi * 4 + r) * 64 + dt * 16 + l15] = o[dt][r];
    if (lhi == 0) {
        ps[1024 + l15] = m;
        ps[1040 + l15] = lsum;
    }
}

// Combine <=4 split-K partials per (b, q-tile).
__global__ __launch_bounds__(256) void attn_reduce(const float* __restrict__ partial,
                                                   float* __restrict__ out) {
    const int bid = blockIdx.x;           // 0..1023
    const int b = bid >> 7, qt = bid & 127;
    const int nc = qt < 32 ? 1 : qt < 64 ? 2 : qt < 96 ? 3 : 4;
    const int base = b * UPB +
        (qt < 32 ? qt : qt < 64 ? 32 + 2 * (qt - 32)
                      : qt < 96 ? 96 + 3 * (qt - 64) : 192 + 4 * (qt - 96));
    const int d = threadIdx.x & 63;
    const int qr = threadIdx.x >> 6;
    for (int i = 0; i < 4; ++i) {
        const int qq = i * 4 + qr;
        float M = -3.0e38f;
        #pragma unroll
        for (int cc = 0; cc < 4; ++cc)
            if (cc < nc) M = fmaxf(M, partial[(size_t)(base + cc) * SLOTF + 1024 + qq]);
        float L = 0.f, acc = 0.f;
        #pragma unroll
        for (int cc = 0; cc < 4; ++cc)
            if (cc < nc) {
                const float* ps = partial + (size_t)(base + cc) * SLOTF;
                float w = exp2f(ps[1024 + qq] - M);
                L += ps[1040 + qq] * w;
                acc += ps[qq * 64 + d] * w;
            }
        out[((size_t)b * Tn + qt * 16 + qq) * Hn + d] = acc / L;
    }
}

extern "C" void kernel_launch(void* const* d_in, const int* in_sizes, int n_in,
                              void* d_out, int out_size, void* d_ws, size_t ws_size,
                              hipStream_t stream) {
    const float* x = (const float*)d_in[0];
    const float* Wq = (const float*)d_in[1];
    const float* Wk = (const float*)d_in[2];
    const float* Wv = (const float*)d_in[3];
    float* out = (float*)d_out;
    char* ws = (char*)d_ws;

    u16* wt = (u16*)ws;                                    // [3][64][1024] bf16   (384 KB)
    u16* qk = (u16*)(ws + 3 * Hn * Cn * 2);                // 2 x [16384][64] bf16 (4 MB)
    u16* vt = qk + 2 * (size_t)Mrows * Hn;                 // [8][64][2048] bf16   (2 MB)
    float* partial = (float*)(ws + 3 * Hn * Cn * 2
                              + 2 * (size_t)Mrows * Hn * 2
                              + (size_t)Bn * Hn * Tn * 2); // 2560 x 1056 f32      (10.8 MB)

    const float qscale = 0.04508422002778011f;  // C^-0.5 * log2(e)
    convert_w3<<<768, 256, 0, stream>>>(Wq, Wk, Wv, wt, qscale);
    qkv_proj<<<1024, 256, 0, stream>>>(x, wt, qk, vt);
    attn_fwd<<<Bn * UPB, 64, 0, stream>>>(qk, qk + (size_t)Mrows * Hn, vt, partial);
    attn_reduce<<<128 * Bn, 256, 0, stream>>>(partial, out);
}